// Round 15
// baseline (979.598 us; speedup 1.0000x reference)
//
#include <hip/hip_runtime.h>
#include <stdint.h>
#include <stddef.h>

#define M_SZ 8192
#define F_DIM 512
#define N_Q 32768

typedef __attribute__((ext_vector_type(4))) float f32x4;
typedef __attribute__((ext_vector_type(8))) __bf16 bf16x8;
typedef __attribute__((ext_vector_type(2))) __bf16 bf16x2;

__device__ __forceinline__ float bits_to_f(unsigned u) {
    union { unsigned u; float f; } v; v.u = u; return v.f;
}
__device__ __forceinline__ unsigned pk_bf16(float a, float b) {
    union { bf16x2 v; unsigned u; } cv;
    cv.v.x = (__bf16)a; cv.v.y = (__bf16)b;
    return cv.u;
}
__device__ __forceinline__ unsigned short f2bf(float x) {
    union { bf16x2 v; unsigned u; } cv;
    cv.v.x = (__bf16)x; cv.v.y = (__bf16)0.0f;
    return (unsigned short)(cv.u & 0xffffu);
}
__device__ __forceinline__ bf16x8 as_bf16x8(uint4 u) {
    union { uint4 a; bf16x8 b; } cv; cv.a = u; return cv.b;
}

// ---------------------------------------------------------------------------
// Kernel 1: row-normalize positions & embeddings; pad to float4.
// ---------------------------------------------------------------------------
__global__ void prep_kernel(const float* __restrict__ pos,
                            const float* __restrict__ emb,
                            float* __restrict__ pn4,
                            float* __restrict__ en4,
                            float* __restrict__ pos4) {
    int i = blockIdx.x * 256 + threadIdx.x;
    if (i >= M_SZ) return;
    float x = pos[i * 3 + 0], y = pos[i * 3 + 1], z = pos[i * 3 + 2];
    float inv = 1.0f / __builtin_amdgcn_sqrtf(x * x + y * y + z * z);
    pn4[i * 4 + 0] = x * inv; pn4[i * 4 + 1] = y * inv;
    pn4[i * 4 + 2] = z * inv; pn4[i * 4 + 3] = 0.0f;
    pos4[i * 4 + 0] = x; pos4[i * 4 + 1] = y;
    pos4[i * 4 + 2] = z; pos4[i * 4 + 3] = 0.0f;
    float ex = emb[i * 3 + 0], ey = emb[i * 3 + 1], ez = emb[i * 3 + 2];
    float einv = 1.0f / __builtin_amdgcn_sqrtf(ex * ex + ey * ey + ez * ez);
    en4[i * 4 + 0] = ex * einv; en4[i * 4 + 1] = ey * einv;
    en4[i * 4 + 2] = ez * einv; en4[i * 4 + 3] = 0.0f;
}

// ---------------------------------------------------------------------------
// Kernel 2: features [8192,512] fp32 -> featT [512,8192] bf16.
// ---------------------------------------------------------------------------
__global__ void transpose_kernel(const float* __restrict__ feat,
                                 unsigned short* __restrict__ featT) {
    __shared__ float tile[64 * 65];
    const int jb = blockIdx.x * 64, fb = blockIdx.y * 64;
    const int t = threadIdx.x;
#pragma unroll
    for (int p = 0; p < 16; ++p) {
        int idx = p * 256 + t;
        int j = idx >> 6, f = idx & 63;
        tile[j * 65 + f] = feat[(size_t)(jb + j) * F_DIM + fb + f];
    }
    __syncthreads();
#pragma unroll
    for (int p = 0; p < 16; ++p) {
        int idx = p * 256 + t;
        int f = idx >> 6, j = idx & 63;
        featT[(size_t)(fb + f) * M_SZ + jb + j] = f2bf(tile[j * 65 + f]);
    }
}

// ---------------------------------------------------------------------------
// Kernel 3 (v7): P-in-LDS (fragment order, conflict-free) + B-direct-to-reg
// + fb-split (XCD-L2-resident B) + 2 blocks/CU (2 barrier domains).
// BM=64, BN=128 (fb=bid&3), BK=32, 256 thr (4 waves partition F, NF=2).
// Grid 512 = 128 mb x 4 fb -> 2 blocks/CU. B-slice/XCD = 2 MB (L2-fit).
// P chunk c = (row>>4)*64 + kchunk*16 + (row&15) at byte c*16: all
// ds_read/write_b128 lane-16B-contiguous (v6-verified zero-conflict).
// ---------------------------------------------------------------------------
__launch_bounds__(256, 2)
__global__ void build_memory_kernel(const float* __restrict__ pn4,
                                    const float* __restrict__ en4,
                                    const float* __restrict__ pos4,
                                    const unsigned short* __restrict__ featT,
                                    unsigned short* __restrict__ memT,
                                    float* __restrict__ npe4) {
    constexpr int BK = 32;
    __shared__ unsigned short pbuf[2][64 * 32];  // 4 KiB/side, fragment order
    __shared__ f32x4 red4[256];
    __shared__ float lbuf[64];

    const int t = threadIdx.x;
    const int wv = t >> 6, l = t & 63;
    const int col = l & 15, quad = l >> 4;
    const int bid = blockIdx.x;
    const int fb = bid & 3;
    const int mb = (bid >> 2) * 64;
    const int r = t & 63, jq = t >> 6;   // P-row, j-group (8 j each)

    const f32x4 pnr = ((const f32x4*)pn4)[mb + r];
    const f32x4* en = (const f32x4*)en4;
    const f32x4* ps = (const f32x4*)pos4;
    const bool donpe = (fb == 0);

    // B pointers: wave wv owns cols fb*128 + wv*32 + nf*16 + col
    const unsigned short* bp[2];
#pragma unroll
    for (int nf = 0; nf < 2; ++nf)
        bp[nf] = featT + (size_t)(fb * 128 + wv * 32 + nf * 16 + col) * M_SZ + quad * 8;

    f32x4 acc[4][2];
    const f32x4 zero4 = {0.f, 0.f, 0.f, 0.f};
#pragma unroll
    for (int mf = 0; mf < 4; ++mf)
#pragma unroll
        for (int nf = 0; nf < 2; ++nf) acc[mf][nf] = zero4;
    float lp = 0.f, nx = 0.f, ny = 0.f, nz = 0.f;

    uint4 vbA[2], vbB[2];
#pragma unroll
    for (int nf = 0; nf < 2; ++nf) vbA[nf] = *(const uint4*)(bp[nf]);

#define B_GEN_P(JB, SIDE)                                                    \
    {                                                                        \
        unsigned us[4];                                                      \
        _Pragma("unroll") for (int i = 0; i < 8; i += 2) {                   \
            int j = (JB) + jq * 8 + i;                                       \
            f32x4 e0 = en[j], e1 = en[j + 1];                                \
            float s0 = fmaf(pnr.x, e0.x, fmaf(pnr.y, e0.y, pnr.z * e0.z));   \
            float s1 = fmaf(pnr.x, e1.x, fmaf(pnr.y, e1.y, pnr.z * e1.z));   \
            float w0 = __builtin_amdgcn_exp2f(s0 * 1.44269504f);             \
            float w1 = __builtin_amdgcn_exp2f(s1 * 1.44269504f);             \
            unsigned u = pk_bf16(w0, w1);                                    \
            us[i >> 1] = u;                                                  \
            float w0r = bits_to_f(u << 16), w1r = bits_to_f(u & 0xffff0000u);\
            lp += w0r + w1r;                                                 \
            if (donpe) {                                                     \
                f32x4 p0 = ps[j], p1 = ps[j + 1];                            \
                nx = fmaf(w0r, p0.x, fmaf(w1r, p1.x, nx));                   \
                ny = fmaf(w0r, p0.y, fmaf(w1r, p1.y, ny));                   \
                nz = fmaf(w0r, p0.z, fmaf(w1r, p1.z, nz));                   \
            }                                                                \
        }                                                                    \
        int c0 = (r >> 4) * 64 + jq * 16 + (r & 15);                         \
        *(uint4*)(&pbuf[SIDE][c0 * 8]) = make_uint4(us[0], us[1], us[2], us[3]); \
    }

#define B_MFMA(VB, SIDE)                                                     \
    {                                                                        \
        _Pragma("unroll") for (int mf = 0; mf < 4; ++mf) {                   \
            bf16x8 a = *(const bf16x8*)(&pbuf[SIDE][(mf * 64 + l) * 8]);     \
            _Pragma("unroll") for (int nf = 0; nf < 2; ++nf)                 \
                acc[mf][nf] = __builtin_amdgcn_mfma_f32_16x16x32_bf16(       \
                    a, as_bf16x8(VB[nf]), acc[mf][nf], 0, 0, 0);             \
        }                                                                    \
    }

#define B_BODY(CUR, NXT, SIDE, JNXT)                                         \
    {                                                                        \
        _Pragma("unroll") for (int nf = 0; nf < 2; ++nf) {                   \
            NXT[nf] = *(const uint4*)(bp[nf] + BK);                          \
            bp[nf] += BK;                                                    \
        }                                                                    \
        B_GEN_P(JNXT, SIDE ^ 1)                                              \
        B_MFMA(CUR, SIDE)                                                    \
        __syncthreads();                                                     \
    }

    B_GEN_P(0, 0)
    __syncthreads();

    int jn = BK;
    for (int kt = 0; kt < 254; kt += 2) {
        B_BODY(vbA, vbB, 0, jn) jn += BK;
        B_BODY(vbB, vbA, 1, jn) jn += BK;
    }
    B_BODY(vbA, vbB, 0, jn)   // computes P(255) -> side 1
    B_MFMA(vbB, 1)            // kt = 255
#undef B_BODY
#undef B_MFMA
#undef B_GEN_P

    f32x4 mine = {nx, ny, nz, lp};
    red4[t] = mine;
    __syncthreads();
    if (t < 64) {
        f32x4 s = red4[t];
#pragma unroll
        for (int g = 1; g < 4; ++g) {
            f32x4 o = red4[t + 64 * g];
            s.x += o.x; s.y += o.y; s.z += o.z; s.w += o.w;
        }
        lbuf[t] = s.w;
        if (donpe) {
            float inv = 1.0f / s.w;
            float X = s.x * inv, Y = s.y * inv, Z = s.z * inv;
            f32x4 o = {X, Y, Z, X * X + Y * Y + Z * Z};
            ((f32x4*)npe4)[mb + t] = o;
        }
    }
    __syncthreads();

    // memT[f][m] = acc/l (D: row m = mf*16 + quad*4 + reg, col f = lane&15)
#pragma unroll
    for (int mf = 0; mf < 4; ++mf) {
        f32x4 l4 = *(const f32x4*)(lbuf + mf * 16 + quad * 4);
        f32x4 inv4 = {1.0f / l4.x, 1.0f / l4.y, 1.0f / l4.z, 1.0f / l4.w};
        int mg = mb + mf * 16 + quad * 4;
#pragma unroll
        for (int nf = 0; nf < 2; ++nf) {
            int fg = fb * 128 + wv * 32 + nf * 16 + col;
            uint2 o;
            o.x = pk_bf16(acc[mf][nf].x * inv4.x, acc[mf][nf].y * inv4.y);
            o.y = pk_bf16(acc[mf][nf].z * inv4.z, acc[mf][nf].w * inv4.w);
            *(uint2*)(memT + (size_t)fg * M_SZ + mg) = o;
        }
    }
}

// ---------------------------------------------------------------------------
// Kernel 4 (v7): P-in-LDS (fragment order) + B-direct-to-reg + fb-split.
// BM=128, BN=256 (fb=bid&1), BK=32, 256 thr (4 waves partition F, NF=4).
// Grid 512 = 256 qb x 2 fb -> 2 blocks/CU (2 staggered barrier domains).
// B working set per fb = 4 MB = one XCD L2. acc = 8x4 f32x4 = 128 regs.
// ---------------------------------------------------------------------------
__launch_bounds__(256, 2)
__global__ void query_kernel(const float* __restrict__ qpos,
                             const float* __restrict__ npe4,
                             const unsigned short* __restrict__ memT,
                             float* __restrict__ out) {
    constexpr int BK = 32;
    __shared__ unsigned short pbuf[2][128 * 32];  // 8 KiB/side, fragment order
    __shared__ float redl[256];
    __shared__ float lbuf[128];

    const int t = threadIdx.x;
    const int wv = t >> 6, l = t & 63;
    const int col = l & 15, quad = l >> 4;
    const int bid = blockIdx.x;
    const int fb = bid & 1;
    const int qb = (bid >> 1) * 128;
    const int r = t & 127, jq = t >> 7;  // P-row, j-group (16 j each)

    const float qx = qpos[(size_t)(qb + r) * 3 + 0];
    const float qy = qpos[(size_t)(qb + r) * 3 + 1];
    const float qz = qpos[(size_t)(qb + r) * 3 + 2];
    const float q2 = qx * qx + qy * qy + qz * qz;
    const float m2x = -2.0f * qx, m2y = -2.0f * qy, m2z = -2.0f * qz;

    const f32x4* nsrc = (const f32x4*)npe4;

    // B pointers: wave wv owns cols fb*256 + wv*64 + nf*16 + col
    const unsigned short* bp[4];
#pragma unroll
    for (int nf = 0; nf < 4; ++nf)
        bp[nf] = memT + (size_t)(fb * 256 + wv * 64 + nf * 16 + col) * M_SZ + quad * 8;

    f32x4 acc[8][4];
    const f32x4 zero4 = {0.f, 0.f, 0.f, 0.f};
#pragma unroll
    for (int mf = 0; mf < 8; ++mf)
#pragma unroll
        for (int nf = 0; nf < 4; ++nf) acc[mf][nf] = zero4;
    float lp = 0.f;

    uint4 vbA[4], vbB[4];
#pragma unroll
    for (int nf = 0; nf < 4; ++nf) vbA[nf] = *(const uint4*)(bp[nf]);

#define Q_GEN_P(JB, SIDE)                                                    \
    {                                                                        \
        unsigned us[8];                                                      \
        _Pragma("unroll") for (int i = 0; i < 16; i += 2) {                  \
            int j = (JB) + jq * 16 + i;                                      \
            f32x4 n0 = nsrc[j], n1 = nsrc[j + 1];                            \
            float s0 = fmaf(m2x, n0.x, fmaf(m2y, n0.y, fmaf(m2z, n0.z, q2 + n0.w))); \
            float s1 = fmaf(m2x, n1.x, fmaf(m2y, n1.y, fmaf(m2z, n1.z, q2 + n1.w))); \
            s0 = fmaxf(s0, 1e-12f); s1 = fmaxf(s1, 1e-12f);                  \
            float w0 = __builtin_amdgcn_exp2f(__builtin_amdgcn_sqrtf(s0) * -1.44269504f); \
            float w1 = __builtin_amdgcn_exp2f(__builtin_amdgcn_sqrtf(s1) * -1.44269504f); \
            unsigned u = pk_bf16(w0, w1);                                    \
            lp += bits_to_f(u << 16) + bits_to_f(u & 0xffff0000u);           \
            us[i >> 1] = u;                                                  \
        }                                                                    \
        int c0 = (r >> 4) * 64 + jq * 32 + (r & 15);                         \
        *(uint4*)(&pbuf[SIDE][c0 * 8]) = make_uint4(us[0], us[1], us[2], us[3]); \
        *(uint4*)(&pbuf[SIDE][(c0 + 16) * 8]) = make_uint4(us[4], us[5], us[6], us[7]); \
    }

#define Q_MFMA(VB, SIDE)                                                     \
    {                                                                        \
        _Pragma("unroll") for (int mf = 0; mf < 8; ++mf) {                   \
            bf16x8 a = *(const bf16x8*)(&pbuf[SIDE][(mf * 64 + l) * 8]);     \
            _Pragma("unroll") for (int nf = 0; nf < 4; ++nf)                 \
                acc[mf][nf] = __builtin_amdgcn_mfma_f32_16x16x32_bf16(       \
                    a, as_bf16x8(VB[nf]), acc[mf][nf], 0, 0, 0);             \
        }                                                                    \
    }

#define Q_BODY(CUR, NXT, SIDE, JNXT)                                         \
    {                                                                        \
        _Pragma("unroll") for (int nf = 0; nf < 4; ++nf) {                   \
            NXT[nf] = *(const uint4*)(bp[nf] + BK);                          \
            bp[nf] += BK;                                                    \
        }                                                                    \
        Q_GEN_P(JNXT, SIDE ^ 1)                                              \
        Q_MFMA(CUR, SIDE)                                                    \
        __syncthreads();                                                     \
    }

    Q_GEN_P(0, 0)
    __syncthreads();

    int jn = BK;
    for (int kt = 0; kt < 254; kt += 2) {
        Q_BODY(vbA, vbB, 0, jn) jn += BK;
        Q_BODY(vbB, vbA, 1, jn) jn += BK;
    }
    Q_BODY(vbA, vbB, 0, jn)   // computes P(255) -> side 1
    Q_MFMA(vbB, 1)            // kt = 255
#undef Q_BODY
#undef Q_MFMA
#undef Q_GEN_P

    redl[t] = lp;
    __syncthreads();
    if (t < 128) lbuf[t] = redl[t] + redl[t + 128];
    __syncthreads();

#pragma unroll
    for (int mf = 0; mf < 8; ++mf) {
        f32x4 l4 = *(const f32x4*)(lbuf + mf * 16 + quad * 4);
        f32x4 inv4 = {1.0f / l4.x, 1.0f / l4.y, 1.0f / l4.z, 1.0f / l4.w};
        int qg = qb + mf * 16 + quad * 4;
#pragma unroll
        for (int nf = 0; nf < 4; ++nf) {
            int fg = fb * 256 + wv * 64 + nf * 16 + col;
            out[(size_t)(qg + 0) * F_DIM + fg] = acc[mf][nf].x * inv4.x;
            out[(size_t)(qg + 1) * F_DIM + fg] = acc[mf][nf].y * inv4.y;
            out[(size_t)(qg + 2) * F_DIM + fg] = acc[mf][nf].z * inv4.z;
            out[(size_t)(qg + 3) * F_DIM + fg] = acc[mf][nf].w * inv4.w;
        }
    }
}

// ---------------------------------------------------------------------------
// Workspace layout (bytes):
//   featT : [0,        8388608)   512x8192 bf16
//   memT  : [8388608, 16777216)   512x8192 bf16
//   npe4  : [16777216,16908288)   8192x4 fp32 (x,y,z,|npe|^2)
//   pn4   : [16908288,17039360)
//   en4   : [17039360,17170432)
//   pos4  : [17170432,17301504)
// ---------------------------------------------------------------------------
extern "C" void kernel_launch(void* const* d_in, const int* in_sizes, int n_in,
                              void* d_out, int out_size, void* d_ws, size_t ws_size,
                              hipStream_t stream) {
    const float* features  = (const float*)d_in[0];
    const float* positions = (const float*)d_in[1];
    const float* qpos      = (const float*)d_in[2];
    const float* pemb      = (const float*)d_in[3];
    float* out = (float*)d_out;
    char* ws = (char*)d_ws;

    unsigned short* featT = (unsigned short*)(ws);
    unsigned short* memT  = (unsigned short*)(ws + 8388608);
    float* npe4 = (float*)(ws + 16777216);
    float* pn4  = (float*)(ws + 16908288);
    float* en4  = (float*)(ws + 17039360);
    float* pos4 = (float*)(ws + 17170432);

    hipLaunchKernelGGL(prep_kernel, dim3(M_SZ / 256), dim3(256), 0, stream,
                       positions, pemb, pn4, en4, pos4);
    hipLaunchKernelGGL(transpose_kernel, dim3(M_SZ / 64, F_DIM / 64), dim3(256), 0, stream,
                       features, featT);
    hipLaunchKernelGGL(build_memory_kernel, dim3((M_SZ / 64) * 4), dim3(256), 0, stream,
                       pn4, en4, pos4, featT, memT, npe4);
    hipLaunchKernelGGL(query_kernel, dim3((N_Q / 128) * 2), dim3(256), 0, stream,
                       qpos, npe4, memT, out);
}